// Round 12
// baseline (55.235 us; speedup 1.0000x reference)
//
#include <hip/hip_runtime.h>
#include <hip/hip_fp16.h>
#include <math.h>

#define C_MAX 2000
#define TPB 512        // 8 waves/block

typedef float f32x4 __attribute__((ext_vector_type(4)));
typedef float f32x2 __attribute__((ext_vector_type(2)));

// ---------- helpers ----------
__device__ __forceinline__ unsigned pkh(float a, float b) {
    union { unsigned u; __half2 h; } x;
    x.h = __floats2half2_rn(a, b);
    return x.u;
}
__device__ __forceinline__ float2 uph(unsigned u) {
    union { unsigned u; __half2 h; } x;
    x.u = u;
    return make_float2(__low2float(x.h), __high2float(x.h));
}

__device__ __forceinline__ void quat_to_R(float q0, float q1, float q2, float q3, float R[9]) {
    float inv = 1.0f / sqrtf(q0 * q0 + q1 * q1 + q2 * q2 + q3 * q3);
    float x = q0 * inv, y = q1 * inv, z = q2 * inv, w = q3 * inv;
    R[0] = 1.0f - 2.0f * (y * y + z * z);
    R[1] = 2.0f * (x * y - w * z);
    R[2] = 2.0f * (x * z + w * y);
    R[3] = 2.0f * (x * y + w * z);
    R[4] = 1.0f - 2.0f * (x * x + z * z);
    R[5] = 2.0f * (y * z - w * x);
    R[6] = 2.0f * (x * z - w * y);
    R[7] = 2.0f * (y * z + w * x);
    R[8] = 1.0f - 2.0f * (x * x + y * y);
}

// ---------- per-camera precompute (24B SoA packing) ----------
__global__ void cam_precompute(const float* __restrict__ base_poses,
                               const float* __restrict__ rel_poses,
                               const float* __restrict__ intr,
                               const int* __restrict__ lookup,
                               uint4* __restrict__ cam4,
                               uint2* __restrict__ cam2,
                               int C) {
    int c = blockIdx.x * blockDim.x + threadIdx.x;
    if (c >= C) return;
    int bpi = lookup[2 * c + 0];
    int rpi = lookup[2 * c + 1];
    bool has_rel = (rpi != -1);
    int rs = has_rel ? rpi : 0;

    const float* bp = base_poses + 7 * bpi;
    float tb0 = bp[0], tb1 = bp[1], tb2 = bp[2];
    float Rb[9];
    quat_to_R(bp[3], bp[4], bp[5], bp[6], Rb);

    const float* rp = rel_poses + 7 * rs;
    float Rr[9];
    quat_to_R(rp[3], rp[4], rp[5], rp[6], Rr);

    float Rf[9], tf0, tf1, tf2;
    if (has_rel) {
        #pragma unroll
        for (int i = 0; i < 3; ++i) {
            #pragma unroll
            for (int j = 0; j < 3; ++j) {
                Rf[3 * i + j] = Rb[3 * i + 0] * Rr[0 + j]
                              + Rb[3 * i + 1] * Rr[3 + j]
                              + Rb[3 * i + 2] * Rr[6 + j];
            }
        }
        tf0 = tb0 + Rb[0] * rp[0] + Rb[1] * rp[1] + Rb[2] * rp[2];
        tf1 = tb1 + Rb[3] * rp[0] + Rb[4] * rp[1] + Rb[5] * rp[2];
        tf2 = tb2 + Rb[6] * rp[0] + Rb[7] * rp[1] + Rb[8] * rp[2];
    } else {
        #pragma unroll
        for (int i = 0; i < 9; ++i) Rf[i] = Rb[i];
        tf0 = tb0; tf1 = tb1; tf2 = tb2;
    }

    const float* K = intr + 9 * c;
    float M[9], v[3];
    #pragma unroll
    for (int i = 0; i < 3; ++i) {
        #pragma unroll
        for (int j = 0; j < 3; ++j) {
            M[3 * i + j] = K[3 * i + 0] * Rf[0 + j]
                         + K[3 * i + 1] * Rf[3 + j]
                         + K[3 * i + 2] * Rf[6 + j];
        }
        v[i] = K[3 * i + 0] * tf0 + K[3 * i + 1] * tf1 + K[3 * i + 2] * tf2;
    }

    uint4 w0;
    uint2 w1;
    w0.x = pkh(M[0], M[1]);
    w0.y = pkh(M[2], M[3]);
    w0.z = pkh(M[4], M[5]);
    w0.w = pkh(M[6], M[7]);
    w1.x = pkh(M[8], v[0]);
    w1.y = pkh(v[1], v[2]);
    cam4[c] = w0;
    cam2[c] = w1;
}

// ---------- pack points to fp16: 8B/point -> 4MB (L2-resident) ----------
__global__ void pack_points(const float* __restrict__ pts, uint2* __restrict__ ph, int P) {
    int i = blockIdx.x * blockDim.x + threadIdx.x;
    if (i < P) {
        float x = pts[3 * i + 0], y = pts[3 * i + 1], z = pts[3 * i + 2];
        uint2 q;
        q.x = pkh(x, y);
        q.y = pkh(z, 0.0f);
        ph[i] = q;
    }
}

// ---------- projection ----------
__device__ __forceinline__ float2 project_one(const uint4& A, const uint2& B,
                                              const uint2& q, float mx, float my) {
    float2 m01 = uph(A.x);
    float2 m23 = uph(A.y);
    float2 m45 = uph(A.z);
    float2 m67 = uph(A.w);
    float2 m8v0 = uph(B.x);
    float2 v12 = uph(B.y);
    float2 xy = uph(q.x);
    float2 zp = uph(q.y);
    float px = xy.x, py = xy.y, pz = zp.x;

    float jx = m01.x * px + m01.y * py + m23.x * pz + m8v0.y;
    float jy = m23.y * px + m45.x * py + m45.y * pz + v12.x;
    float jz = m67.x * px + m67.y * py + m8v0.x * pz + v12.y;
    float iz = 1.0f / jz;
    return make_float2(jx * iz - mx, jy * iz - my);
}

// One full wave-strided pass of depth D starting at obs index i (all rows full).
// LDS reads live in the compute loop: lgkmcnt is independent of vmcnt, LDS
// latency (~120cy) needs no deep pipelining — keeps the live set small.
template <int D>
__device__ __forceinline__ void pass(long i, int wave, int lane,
                                     const f32x4* __restrict__ obsv,
                                     const uint2* __restrict__ pts,
                                     const uint4* s4, const uint2* s2,
                                     float2* __restrict__ out) {
    long base = i + (long)wave * (64 * D) + lane;

    f32x4 o[D];
    #pragma unroll
    for (int k = 0; k < D; ++k)
        o[k] = __builtin_nontemporal_load(&obsv[base + 64 * k]);

    int ci[D], pi[D];
    float mx[D], my[D];
    #pragma unroll
    for (int k = 0; k < D; ++k) {
        ci[k] = (int)o[k].x;
        pi[k] = (int)o[k].y;
        mx[k] = o[k].z;
        my[k] = o[k].w;
    }

    uint2 q[D];
    #pragma unroll
    for (int k = 0; k < D; ++k) q[k] = pts[pi[k]];

    // pin: compute may not be hoisted above the gather issues
    __builtin_amdgcn_sched_barrier(0);

    #pragma unroll
    for (int k = 0; k < D; ++k) {
        uint4 A = s4[ci[k]];
        uint2 B = s2[ci[k]];
        float2 r = project_one(A, B, q[k], mx[k], my[k]);
        f32x2 w = {r.x, r.y};
        __builtin_nontemporal_store(w, (f32x2*)&out[base + 64 * k]);
    }
}

__launch_bounds__(TPB, 4)
__global__ void residual_d12(const f32x4* __restrict__ obsv,
                             const uint2* __restrict__ pts,
                             const uint4* __restrict__ cam4g,
                             const uint2* __restrict__ cam2g,
                             float2* __restrict__ out,
                             long N,
                             int C,
                             long per_block) {
    long r0 = (long)blockIdx.x * per_block;
    if (r0 >= N) return;

    __shared__ uint4 s4[C_MAX];   // 32 KB
    __shared__ uint2 s2[C_MAX];   // 16 KB
    for (int i = threadIdx.x; i < C; i += blockDim.x) {
        s4[i] = cam4g[i];
        s2[i] = cam2g[i];
    }
    __syncthreads();

    long r1 = r0 + per_block;
    if (r1 > N) r1 = N;

    int wave = threadIdx.x >> 6;
    int lane = threadIdx.x & 63;

    long i = r0;
    // deep passes first (identical hot-path style to round 9/11, depth 12)
    for (; i + (long)TPB * 12 <= r1; i += (long)TPB * 12)
        pass<12>(i, wave, lane, obsv, pts, s4, s2, out);
    if (i + (long)TPB * 8 <= r1) {
        pass<8>(i, wave, lane, obsv, pts, s4, s2, out);
        i += (long)TPB * 8;
    }
    if (i + (long)TPB * 4 <= r1) {
        pass<4>(i, wave, lane, obsv, pts, s4, s2, out);
        i += (long)TPB * 4;
    }
    if (i + (long)TPB * 2 <= r1) {
        pass<2>(i, wave, lane, obsv, pts, s4, s2, out);
        i += (long)TPB * 2;
    }
    if (i + (long)TPB <= r1) {
        pass<1>(i, wave, lane, obsv, pts, s4, s2, out);
        i += (long)TPB;
    }
    // final sliver (<512 obs)
    for (long j = i + threadIdx.x; j < r1; j += TPB) {
        f32x4 ob = obsv[j];
        int c = (int)ob.x;
        int pt = (int)ob.y;
        uint4 A = s4[c];
        uint2 B = s2[c];
        uint2 q = pts[pt];
        float2 r = project_one(A, B, q, ob.z, ob.w);
        out[j] = r;
    }
}

extern "C" void kernel_launch(void* const* d_in, const int* in_sizes, int n_in,
                              void* d_out, int out_size, void* d_ws, size_t ws_size,
                              hipStream_t stream) {
    const float* obs = (const float*)d_in[0];
    const float* base_poses = (const float*)d_in[1];
    const float* rel_poses = (const float*)d_in[2];
    const float* points = (const float*)d_in[3];
    const float* intr = (const float*)d_in[4];
    const int* lookup = (const int*)d_in[5];

    long N = in_sizes[0] / 4;   // observations
    int P = in_sizes[3] / 3;    // points
    int C = in_sizes[5] / 2;    // cameras

    // ws layout: [0,32K) cam4 ; [32K,48K) cam2 ; [48K, 48K+8P) fp16 points
    uint4* cam4 = (uint4*)d_ws;
    uint2* cam2 = (uint2*)((char*)d_ws + (size_t)C_MAX * 16);
    uint2* pts_h = (uint2*)((char*)d_ws + (size_t)C_MAX * 24);

    cam_precompute<<<(C + 255) / 256, 256, 0, stream>>>(
        base_poses, rel_poses, intr, lookup, cam4, cam2, C);
    pack_points<<<(P + 255) / 256, 256, 0, stream>>>(points, pts_h, P);

    // one depth-12 pass per block; tail block handles the remainder
    long per_block = (long)TPB * 12;                      // 6144
    int blocks = (int)((N + per_block - 1) / per_block);  // 652 @ N=4M
    residual_d12<<<blocks, TPB, 0, stream>>>(
        (const f32x4*)obs, pts_h, cam4, cam2, (float2*)d_out, N, C, per_block);
}

// Round 13
// 50.207 us; speedup vs baseline: 1.1001x; 1.1001x over previous
//
#include <hip/hip_runtime.h>
#include <hip/hip_fp16.h>
#include <math.h>

#define C_MAX 2000
#define TPB 512        // 8 waves/block
#define NBLOCKS 768    // 3 blocks/CU x 256 CU

typedef float f32x4 __attribute__((ext_vector_type(4)));
typedef float f32x2 __attribute__((ext_vector_type(2)));

// ---------- helpers ----------
__device__ __forceinline__ unsigned pkh(float a, float b) {
    union { unsigned u; __half2 h; } x;
    x.h = __floats2half2_rn(a, b);
    return x.u;
}
__device__ __forceinline__ float2 uph(unsigned u) {
    union { unsigned u; __half2 h; } x;
    x.u = u;
    return make_float2(__low2float(x.h), __high2float(x.h));
}

__device__ __forceinline__ void quat_to_R(float q0, float q1, float q2, float q3, float R[9]) {
    float inv = 1.0f / sqrtf(q0 * q0 + q1 * q1 + q2 * q2 + q3 * q3);
    float x = q0 * inv, y = q1 * inv, z = q2 * inv, w = q3 * inv;
    R[0] = 1.0f - 2.0f * (y * y + z * z);
    R[1] = 2.0f * (x * y - w * z);
    R[2] = 2.0f * (x * z + w * y);
    R[3] = 2.0f * (x * y + w * z);
    R[4] = 1.0f - 2.0f * (x * x + z * z);
    R[5] = 2.0f * (y * z - w * x);
    R[6] = 2.0f * (x * z - w * y);
    R[7] = 2.0f * (y * z + w * x);
    R[8] = 1.0f - 2.0f * (x * x + y * y);
}

// ---------- per-camera precompute (24B SoA packing) ----------
__global__ void cam_precompute(const float* __restrict__ base_poses,
                               const float* __restrict__ rel_poses,
                               const float* __restrict__ intr,
                               const int* __restrict__ lookup,
                               uint4* __restrict__ cam4,
                               uint2* __restrict__ cam2,
                               int C) {
    int c = blockIdx.x * blockDim.x + threadIdx.x;
    if (c >= C) return;
    int bpi = lookup[2 * c + 0];
    int rpi = lookup[2 * c + 1];
    bool has_rel = (rpi != -1);
    int rs = has_rel ? rpi : 0;

    const float* bp = base_poses + 7 * bpi;
    float tb0 = bp[0], tb1 = bp[1], tb2 = bp[2];
    float Rb[9];
    quat_to_R(bp[3], bp[4], bp[5], bp[6], Rb);

    const float* rp = rel_poses + 7 * rs;
    float Rr[9];
    quat_to_R(rp[3], rp[4], rp[5], rp[6], Rr);

    float Rf[9], tf0, tf1, tf2;
    if (has_rel) {
        #pragma unroll
        for (int i = 0; i < 3; ++i) {
            #pragma unroll
            for (int j = 0; j < 3; ++j) {
                Rf[3 * i + j] = Rb[3 * i + 0] * Rr[0 + j]
                              + Rb[3 * i + 1] * Rr[3 + j]
                              + Rb[3 * i + 2] * Rr[6 + j];
            }
        }
        tf0 = tb0 + Rb[0] * rp[0] + Rb[1] * rp[1] + Rb[2] * rp[2];
        tf1 = tb1 + Rb[3] * rp[0] + Rb[4] * rp[1] + Rb[5] * rp[2];
        tf2 = tb2 + Rb[6] * rp[0] + Rb[7] * rp[1] + Rb[8] * rp[2];
    } else {
        #pragma unroll
        for (int i = 0; i < 9; ++i) Rf[i] = Rb[i];
        tf0 = tb0; tf1 = tb1; tf2 = tb2;
    }

    const float* K = intr + 9 * c;
    float M[9], v[3];
    #pragma unroll
    for (int i = 0; i < 3; ++i) {
        #pragma unroll
        for (int j = 0; j < 3; ++j) {
            M[3 * i + j] = K[3 * i + 0] * Rf[0 + j]
                         + K[3 * i + 1] * Rf[3 + j]
                         + K[3 * i + 2] * Rf[6 + j];
        }
        v[i] = K[3 * i + 0] * tf0 + K[3 * i + 1] * tf1 + K[3 * i + 2] * tf2;
    }

    uint4 w0;
    uint2 w1;
    w0.x = pkh(M[0], M[1]);
    w0.y = pkh(M[2], M[3]);
    w0.z = pkh(M[4], M[5]);
    w0.w = pkh(M[6], M[7]);
    w1.x = pkh(M[8], v[0]);
    w1.y = pkh(v[1], v[2]);
    cam4[c] = w0;
    cam2[c] = w1;
}

// ---------- pack points to fp16: 8B/point -> 4MB (L2-resident) ----------
__global__ void pack_points(const float* __restrict__ pts, uint2* __restrict__ ph, int P) {
    int i = blockIdx.x * blockDim.x + threadIdx.x;
    if (i < P) {
        float x = pts[3 * i + 0], y = pts[3 * i + 1], z = pts[3 * i + 2];
        uint2 q;
        q.x = pkh(x, y);
        q.y = pkh(z, 0.0f);
        ph[i] = q;
    }
}

// ---------- projection ----------
__device__ __forceinline__ float2 project_one(const uint4& A, const uint2& B,
                                              const uint2& q, float mx, float my) {
    float2 m01 = uph(A.x);
    float2 m23 = uph(A.y);
    float2 m45 = uph(A.z);
    float2 m67 = uph(A.w);
    float2 m8v0 = uph(B.x);
    float2 v12 = uph(B.y);
    float2 xy = uph(q.x);
    float2 zp = uph(q.y);
    float px = xy.x, py = xy.y, pz = zp.x;

    float jx = m01.x * px + m01.y * py + m23.x * pz + m8v0.y;
    float jy = m23.y * px + m45.x * py + m45.y * pz + v12.x;
    float jz = m67.x * px + m67.y * py + m8v0.x * pz + v12.y;
    float iz = 1.0f / jz;
    return make_float2(jx * iz - mx, jy * iz - my);
}

// One full wave-strided pass of depth D starting at obs index i (all rows full).
// obs loads are CACHED (L3-resident in steady state); stores stay NT.
template <int D>
__device__ __forceinline__ void pass(long i, int wave, int lane,
                                     const f32x4* __restrict__ obsv,
                                     const uint2* __restrict__ pts,
                                     const uint4* s4, const uint2* s2,
                                     float2* __restrict__ out) {
    long base = i + (long)wave * (64 * D) + lane;

    f32x4 o[D];
    #pragma unroll
    for (int k = 0; k < D; ++k)
        o[k] = obsv[base + 64 * k];          // cached load (was NT)

    int ci[D], pi[D];
    #pragma unroll
    for (int k = 0; k < D; ++k) {
        ci[k] = (int)o[k].x;
        pi[k] = (int)o[k].y;
    }

    uint2 q[D];
    #pragma unroll
    for (int k = 0; k < D; ++k) q[k] = pts[pi[k]];

    uint4 A[D];
    uint2 B[D];
    #pragma unroll
    for (int k = 0; k < D; ++k) {
        A[k] = s4[ci[k]];
        B[k] = s2[ci[k]];
    }

    __builtin_amdgcn_sched_barrier(0);

    #pragma unroll
    for (int k = 0; k < D; ++k) {
        float2 r = project_one(A[k], B[k], q[k], o[k].z, o[k].w);
        f32x2 w = {r.x, r.y};
        __builtin_nontemporal_store(w, (f32x2*)&out[base + 64 * k]);
    }
}

__launch_bounds__(TPB, 4)
__global__ void residual_c(const f32x4* __restrict__ obsv,
                           const uint2* __restrict__ pts,
                           const uint4* __restrict__ cam4g,
                           const uint2* __restrict__ cam2g,
                           float2* __restrict__ out,
                           long N,
                           int C,
                           long per_block) {
    long r0 = (long)blockIdx.x * per_block;
    if (r0 >= N) return;

    __shared__ uint4 s4[C_MAX];   // 32 KB
    __shared__ uint2 s2[C_MAX];   // 16 KB
    for (int i = threadIdx.x; i < C; i += blockDim.x) {
        s4[i] = cam4g[i];
        s2[i] = cam2g[i];
    }
    __syncthreads();

    long r1 = r0 + per_block;
    if (r1 > N) r1 = N;

    int wave = threadIdx.x >> 6;
    int lane = threadIdx.x & 63;

    long i = r0;
    for (; i + (long)TPB * 8 <= r1; i += (long)TPB * 8)
        pass<8>(i, wave, lane, obsv, pts, s4, s2, out);
    if (i + (long)TPB * 4 <= r1) {
        pass<4>(i, wave, lane, obsv, pts, s4, s2, out);
        i += (long)TPB * 4;
    }
    if (i + (long)TPB * 2 <= r1) {
        pass<2>(i, wave, lane, obsv, pts, s4, s2, out);
        i += (long)TPB * 2;
    }
    if (i + (long)TPB <= r1) {
        pass<1>(i, wave, lane, obsv, pts, s4, s2, out);
        i += (long)TPB;
    }
    for (long j = i + threadIdx.x; j < r1; j += TPB) {
        f32x4 ob = obsv[j];
        int c = (int)ob.x;
        int pt = (int)ob.y;
        uint4 A = s4[c];
        uint2 B = s2[c];
        uint2 q = pts[pt];
        float2 r = project_one(A, B, q, ob.z, ob.w);
        out[j] = r;
    }
}

extern "C" void kernel_launch(void* const* d_in, const int* in_sizes, int n_in,
                              void* d_out, int out_size, void* d_ws, size_t ws_size,
                              hipStream_t stream) {
    const float* obs = (const float*)d_in[0];
    const float* base_poses = (const float*)d_in[1];
    const float* rel_poses = (const float*)d_in[2];
    const float* points = (const float*)d_in[3];
    const float* intr = (const float*)d_in[4];
    const int* lookup = (const int*)d_in[5];

    long N = in_sizes[0] / 4;   // observations
    int P = in_sizes[3] / 3;    // points
    int C = in_sizes[5] / 2;    // cameras

    // ws layout: [0,32K) cam4 ; [32K,48K) cam2 ; [48K, 48K+8P) fp16 points
    uint4* cam4 = (uint4*)d_ws;
    uint2* cam2 = (uint2*)((char*)d_ws + (size_t)C_MAX * 16);
    uint2* pts_h = (uint2*)((char*)d_ws + (size_t)C_MAX * 24);

    cam_precompute<<<(C + 255) / 256, 256, 0, stream>>>(
        base_poses, rel_poses, intr, lookup, cam4, cam2, C);
    pack_points<<<(P + 255) / 256, 256, 0, stream>>>(points, pts_h, P);

    // balanced contiguous 64-aligned ranges, <= NBLOCKS blocks
    long per_block = (N + (long)NBLOCKS - 1) / NBLOCKS;   // ~5209
    per_block = (per_block + 63) / 64 * 64;               // 5248
    int blocks = (int)((N + per_block - 1) / per_block);  // 763
    residual_c<<<blocks, TPB, 0, stream>>>(
        (const f32x4*)obs, pts_h, cam4, cam2, (float2*)d_out, N, C, per_block);
}